// Round 1
// baseline (122.840 us; speedup 1.0000x reference)
//
#include <hip/hip_runtime.h>
#include <hip/hip_bf16.h>

typedef __attribute__((ext_vector_type(8))) short short8;
typedef __attribute__((ext_vector_type(4))) float f32x4;

#define B_DIM   8192
#define IN_DIM  2048
#define OUT_DIM 1024
#define K_DIM   (2 * IN_DIM)   // 4096: [masked x | -|x|] concat along K

__device__ __forceinline__ unsigned short f2bf(float f) {
    union { float f; unsigned u; } v; v.f = f;
    unsigned u = v.u;
    // round-to-nearest-even bf16
    unsigned r = (u + 0x7FFFu + ((u >> 16) & 1u)) >> 16;
    return (unsigned short)r;
}

// A'[b][i]        = x[b][i] if x >= -1 else 0
// A'[b][IN + i]   = -|x[b][i]|
__global__ void prep_x(const float* __restrict__ x, unsigned short* __restrict__ A) {
    const int n8 = B_DIM * IN_DIM / 8;   // 2,097,152
    for (int v = blockIdx.x * blockDim.x + threadIdx.x; v < n8;
         v += gridDim.x * blockDim.x) {
        const float4* xp = reinterpret_cast<const float4*>(x) + (size_t)v * 2;
        float4 lo = xp[0], hi = xp[1];
        float xs[8] = {lo.x, lo.y, lo.z, lo.w, hi.x, hi.y, hi.z, hi.w};
        short8 mv, av;
        #pragma unroll
        for (int j = 0; j < 8; ++j) {
            float xf = xs[j];
            mv[j] = (short)f2bf(xf >= -1.0f ? xf : 0.0f);
            av[j] = (short)f2bf(-fabsf(xf));
        }
        int b  = v >> 8;        // IN_DIM/8 = 256 chunks per row
        int i8 = v & 255;
        *reinterpret_cast<short8*>(A + (size_t)b * K_DIM + i8 * 8)          = mv;
        *reinterpret_cast<short8*>(A + (size_t)b * K_DIM + IN_DIM + i8 * 8) = av;
    }
}

// Bt[o][i]        = W[i][o]
// Bt[o][IN + i]   = 0.1 * |W[i][o]|        (DELTA folded in)
__global__ void prep_w(const float* __restrict__ W, unsigned short* __restrict__ Bt) {
    __shared__ float tile[32][33];
    int o0 = blockIdx.x * 32;
    int i0 = blockIdx.y * 32;
    int tx = threadIdx.x, ty = threadIdx.y;   // 32 x 8
    #pragma unroll
    for (int r = 0; r < 4; ++r) {
        int ii = ty + r * 8;
        tile[ii][tx] = W[(size_t)(i0 + ii) * OUT_DIM + o0 + tx];
    }
    __syncthreads();
    #pragma unroll
    for (int r = 0; r < 4; ++r) {
        int oo = ty + r * 8;
        float wv = tile[tx][oo];
        Bt[(size_t)(o0 + oo) * K_DIM + i0 + tx]          = f2bf(wv);
        Bt[(size_t)(o0 + oo) * K_DIM + IN_DIM + i0 + tx] = f2bf(0.1f * fabsf(wv));
    }
}

#define BM 128
#define BN 128
#define BK 64

// out[b][o] = sum_k A'[b][k] * Bt[o][k] + 1e-5
__global__ void gemm_fused(const unsigned short* __restrict__ A,
                           const unsigned short* __restrict__ Bt,
                           float* __restrict__ C) {
    __shared__ __align__(16) unsigned short sA[BM * BK];  // [128][64] row-major (m, k)
    __shared__ __align__(16) unsigned short sB[BN * BK];  // [128][64] row-major (n, k)

    int bid = blockIdx.x;
    int bx = bid >> 6;    // 0..7   N-tile (consecutive bids share the B panel)
    int by = bid & 63;    // 0..63  M-tile
    int row0 = by * BM;
    int col0 = bx * BN;
    int tid  = threadIdx.x;
    int lane = tid & 63;
    int w    = tid >> 6;          // wave 0..3
    int wr   = w >> 1, wc = w & 1;

    f32x4 acc[4][4];
    #pragma unroll
    for (int m = 0; m < 4; ++m)
        #pragma unroll
        for (int n = 0; n < 4; ++n)
            acc[m][n] = (f32x4){0.f, 0.f, 0.f, 0.f};

    const int nsteps = K_DIM / BK;   // 64
    for (int t = 0; t < nsteps; ++t) {
        int k0 = t * BK;
        // Stage A tile: 16 KB via 4 x (256 threads x 16B) global_load_lds
        #pragma unroll
        for (int it = 0; it < 4; ++it) {
            int cbase = it * 256 + (tid & ~63);          // wave-uniform chunk base
            int c  = cbase + (tid & 63);
            int r  = c >> 3;                             // row within tile
            int c8 = (c & 7) << 3;                       // k offset (8 bf16 = 16B)
            __builtin_amdgcn_global_load_lds(
                (const __attribute__((address_space(1))) void*)(A + (size_t)(row0 + r) * K_DIM + k0 + c8),
                (__attribute__((address_space(3))) void*)(sA + (size_t)cbase * 8),
                16, 0, 0);
        }
        // Stage B tile (Bt is n-major, so identical pattern)
        #pragma unroll
        for (int it = 0; it < 4; ++it) {
            int cbase = it * 256 + (tid & ~63);
            int c  = cbase + (tid & 63);
            int r  = c >> 3;
            int c8 = (c & 7) << 3;
            __builtin_amdgcn_global_load_lds(
                (const __attribute__((address_space(1))) void*)(Bt + (size_t)(col0 + r) * K_DIM + k0 + c8),
                (__attribute__((address_space(3))) void*)(sB + (size_t)cbase * 8),
                16, 0, 0);
        }
        __syncthreads();

        int lr = lane & 15;
        int lk = (lane >> 4) << 3;   // k-offset of this lane's 8 contiguous elements
        #pragma unroll
        for (int kk = 0; kk < 2; ++kk) {
            short8 a_frag[4], b_frag[4];
            #pragma unroll
            for (int m = 0; m < 4; ++m)
                a_frag[m] = *reinterpret_cast<const short8*>(
                    sA + (wr * 64 + m * 16 + lr) * BK + kk * 32 + lk);
            #pragma unroll
            for (int n = 0; n < 4; ++n)
                b_frag[n] = *reinterpret_cast<const short8*>(
                    sB + (wc * 64 + n * 16 + lr) * BK + kk * 32 + lk);
            #pragma unroll
            for (int m = 0; m < 4; ++m)
                #pragma unroll
                for (int n = 0; n < 4; ++n)
                    acc[m][n] = __builtin_amdgcn_mfma_f32_16x16x32_bf16(
                        a_frag[m], b_frag[n], acc[m][n], 0, 0, 0);
        }
        __syncthreads();
    }

    // Epilogue: C/D layout col = lane&15, row = (lane>>4)*4 + reg
    int lr = lane & 15, lq = lane >> 4;
    #pragma unroll
    for (int m = 0; m < 4; ++m) {
        #pragma unroll
        for (int n = 0; n < 4; ++n) {
            int col  = col0 + wc * 64 + n * 16 + lr;
            int rowb = row0 + wr * 64 + m * 16 + lq * 4;
            #pragma unroll
            for (int j = 0; j < 4; ++j)
                C[(size_t)(rowb + j) * OUT_DIM + col] = acc[m][n][j] + 1e-5f;
        }
    }
}

extern "C" void kernel_launch(void* const* d_in, const int* in_sizes, int n_in,
                              void* d_out, int out_size, void* d_ws, size_t ws_size,
                              hipStream_t stream) {
    const float* x = (const float*)d_in[0];
    const float* W = (const float*)d_in[1];
    float* out = (float*)d_out;

    unsigned short* A  = (unsigned short*)d_ws;                              // 64 MB
    unsigned short* Bt = (unsigned short*)d_ws + (size_t)B_DIM * K_DIM;      // + 8 MB

    prep_x<<<4096, 256, 0, stream>>>(x, A);
    prep_w<<<dim3(OUT_DIM / 32, IN_DIM / 32), dim3(32, 8), 0, stream>>>(W, Bt);
    gemm_fused<<<(B_DIM / BM) * (OUT_DIM / BN), 256, 0, stream>>>(A, Bt, out);
}

// Round 2
// 107.104 us; speedup vs baseline: 1.1469x; 1.1469x over previous
//
#include <hip/hip_runtime.h>
#include <hip/hip_bf16.h>

typedef __attribute__((ext_vector_type(8))) short short8;
typedef __attribute__((ext_vector_type(4))) float f32x4;

#define B_DIM   8192
#define IN_DIM  2048
#define OUT_DIM 1024
#define K_DIM   (2 * IN_DIM)   // 4096: [masked x | -|x|] concat along K

#define BM 256
#define BN 128
#define BK 64
#define NT (K_DIM / BK)            // 64 K-tiles
#define A_TILE_E (BM * BK)         // 16384 bf16 elems = 32 KB
#define B_TILE_E (BN * BK)         // 8192  bf16 elems = 16 KB
#define NBUF 3
#define LDS_BYTES ((A_TILE_E + B_TILE_E) * NBUF * 2)   // 147456 = 144 KiB

__device__ __forceinline__ unsigned short f2bf(float f) {
    union { float f; unsigned u; } v; v.f = f;
    unsigned u = v.u;
    unsigned r = (u + 0x7FFFu + ((u >> 16) & 1u)) >> 16;   // RNE
    return (unsigned short)r;
}

// A'[b][i] = x[b][i] if x >= -1 else 0 ; A'[b][IN+i] = -|x[b][i]|
__global__ void prep_x(const float* __restrict__ x, unsigned short* __restrict__ A) {
    const int n8 = B_DIM * IN_DIM / 8;
    for (int v = blockIdx.x * blockDim.x + threadIdx.x; v < n8;
         v += gridDim.x * blockDim.x) {
        const float4* xp = reinterpret_cast<const float4*>(x) + (size_t)v * 2;
        float4 lo = xp[0], hi = xp[1];
        float xs[8] = {lo.x, lo.y, lo.z, lo.w, hi.x, hi.y, hi.z, hi.w};
        short8 mv, av;
        #pragma unroll
        for (int j = 0; j < 8; ++j) {
            float xf = xs[j];
            mv[j] = (short)f2bf(xf >= -1.0f ? xf : 0.0f);
            av[j] = (short)f2bf(-fabsf(xf));
        }
        int b  = v >> 8;
        int i8 = v & 255;
        *reinterpret_cast<short8*>(A + (size_t)b * K_DIM + i8 * 8)          = mv;
        *reinterpret_cast<short8*>(A + (size_t)b * K_DIM + IN_DIM + i8 * 8) = av;
    }
}

// Bt[o][i] = W[i][o] ; Bt[o][IN+i] = 0.1*|W[i][o]|
__global__ void prep_w(const float* __restrict__ W, unsigned short* __restrict__ Bt) {
    __shared__ float tile[32][33];
    int o0 = blockIdx.x * 32;
    int i0 = blockIdx.y * 32;
    int tx = threadIdx.x, ty = threadIdx.y;   // 32 x 8
    #pragma unroll
    for (int r = 0; r < 4; ++r) {
        int ii = ty + r * 8;
        tile[ii][tx] = W[(size_t)(i0 + ii) * OUT_DIM + o0 + tx];
    }
    __syncthreads();
    #pragma unroll
    for (int r = 0; r < 4; ++r) {
        int oo = ty + r * 8;
        float wv = tile[tx][oo];
        Bt[(size_t)(o0 + oo) * K_DIM + i0 + tx]          = f2bf(wv);
        Bt[(size_t)(o0 + oo) * K_DIM + IN_DIM + i0 + tx] = f2bf(0.1f * fabsf(wv));
    }
}

// ---- staging: linear LDS dest (global_load_lds requirement), XOR-swizzled
// global SOURCE slot; ds_read applies the same involution (rule 21). ----
__device__ __forceinline__ void stage_round(const unsigned short* __restrict__ gsrc,
                                            unsigned short* lds_base,
                                            int row_base, int k0, int r, int tid) {
    int c    = r * 512 + tid;
    int row  = c >> 3;                       // 8 chunks (of 8 bf16) per 64-elem row
    int slot = (c & 7) ^ (row & 7);          // swizzled 16B slot in source
    __builtin_amdgcn_global_load_lds(
        (const __attribute__((address_space(1))) void*)(gsrc + (size_t)(row_base + row) * K_DIM + k0 + slot * 8),
        (__attribute__((address_space(3))) void*)(lds_base + (size_t)c * 8),
        16, 0, 0);
}

// out[b][o] = sum_k A'[b][k] * Bt[o][k] + 1e-5
__global__ __launch_bounds__(512) void gemm_fused(const unsigned short* __restrict__ A,
                                                  const unsigned short* __restrict__ Bt,
                                                  float* __restrict__ C) {
    extern __shared__ __align__(16) unsigned short smem[];
    unsigned short* sA = smem;                       // [3][16384]
    unsigned short* sB = smem + NBUF * A_TILE_E;     // [3][8192]

    int bid  = blockIdx.x;
    int bx   = bid & 7;            // N-tile: XCD round-robin keeps one B-panel per XCD L2
    int by   = bid >> 3;           // M-tile
    int row0 = by * BM;
    int col0 = bx * BN;
    int tid  = threadIdx.x;
    int lane = tid & 63;
    int w    = tid >> 6;           // 0..7
    int wr   = w >> 1;             // 0..3 : 64-row group
    int wc   = w & 1;              // 0..1 : 64-col group
    int lr   = lane & 15;
    int lq   = lane >> 4;          // 0..3

    f32x4 acc[4][4];
    #pragma unroll
    for (int m = 0; m < 4; ++m)
        #pragma unroll
        for (int n = 0; n < 4; ++n)
            acc[m][n] = (f32x4){0.f, 0.f, 0.f, 0.f};

    // prologue: stage tiles 0 and 1
    #pragma unroll
    for (int r = 0; r < 4; ++r) stage_round(A,  sA,             row0, 0,  r, tid);
    #pragma unroll
    for (int r = 0; r < 2; ++r) stage_round(Bt, sB,             col0, 0,  r, tid);
    #pragma unroll
    for (int r = 0; r < 4; ++r) stage_round(A,  sA + A_TILE_E,  row0, BK, r, tid);
    #pragma unroll
    for (int r = 0; r < 2; ++r) stage_round(Bt, sB + B_TILE_E,  col0, BK, r, tid);
    asm volatile("s_waitcnt vmcnt(6)" ::: "memory");   // tile 0 resident
    __builtin_amdgcn_s_barrier();

    int c = 0;
    for (int t = 0; t < NT; ++t) {
        unsigned short* bufA = sA + c * A_TILE_E;
        unsigned short* bufB = sB + c * B_TILE_E;
        int c2 = c + 2; if (c2 >= NBUF) c2 -= NBUF;
        int k2 = (t + 2) * BK;
        bool pf = (t + 2) < NT;

        // ---------------- phase 1 (kk = 0) ----------------
        short8 af[4], bf[4];
        #pragma unroll
        for (int m = 0; m < 4; ++m) {
            int ra = wr * 64 + m * 16 + lr;
            int sl = (0 * 4 + lq) ^ (ra & 7);
            af[m] = *reinterpret_cast<const short8*>(bufA + ra * BK + (sl << 3));
        }
        #pragma unroll
        for (int n = 0; n < 4; ++n) {
            int rb = wc * 64 + n * 16 + lr;
            int sl = (0 * 4 + lq) ^ (rb & 7);
            bf[n] = *reinterpret_cast<const short8*>(bufB + rb * BK + (sl << 3));
        }
        if (pf) {   // 3 of 6 prefetch rounds for tile t+2
            stage_round(A, sA + c2 * A_TILE_E, row0, k2, 0, tid);
            stage_round(A, sA + c2 * A_TILE_E, row0, k2, 1, tid);
            stage_round(A, sA + c2 * A_TILE_E, row0, k2, 2, tid);
        }
        __builtin_amdgcn_s_barrier();
        asm volatile("s_waitcnt lgkmcnt(0)" ::: "memory");
        __builtin_amdgcn_sched_barrier(0);
        __builtin_amdgcn_s_setprio(1);
        #pragma unroll
        for (int m = 0; m < 4; ++m)
            #pragma unroll
            for (int n = 0; n < 4; ++n)
                acc[m][n] = __builtin_amdgcn_mfma_f32_16x16x32_bf16(af[m], bf[n], acc[m][n], 0, 0, 0);
        __builtin_amdgcn_s_setprio(0);
        __builtin_amdgcn_s_barrier();

        // ---------------- phase 2 (kk = 1) ----------------
        #pragma unroll
        for (int m = 0; m < 4; ++m) {
            int ra = wr * 64 + m * 16 + lr;
            int sl = (4 + lq) ^ (ra & 7);
            af[m] = *reinterpret_cast<const short8*>(bufA + ra * BK + (sl << 3));
        }
        #pragma unroll
        for (int n = 0; n < 4; ++n) {
            int rb = wc * 64 + n * 16 + lr;
            int sl = (4 + lq) ^ (rb & 7);
            bf[n] = *reinterpret_cast<const short8*>(bufB + rb * BK + (sl << 3));
        }
        if (pf) {   // remaining 3 rounds for tile t+2
            stage_round(A,  sA + c2 * A_TILE_E, row0, k2, 3, tid);
            stage_round(Bt, sB + c2 * B_TILE_E, col0, k2, 0, tid);
            stage_round(Bt, sB + c2 * B_TILE_E, col0, k2, 1, tid);
            // keep t+2's 6 rounds in flight; force t+1's complete
            asm volatile("s_waitcnt vmcnt(6)" ::: "memory");
        } else {
            asm volatile("s_waitcnt vmcnt(0)" ::: "memory");
        }
        __builtin_amdgcn_s_barrier();
        asm volatile("s_waitcnt lgkmcnt(0)" ::: "memory");
        __builtin_amdgcn_sched_barrier(0);
        __builtin_amdgcn_s_setprio(1);
        #pragma unroll
        for (int m = 0; m < 4; ++m)
            #pragma unroll
            for (int n = 0; n < 4; ++n)
                acc[m][n] = __builtin_amdgcn_mfma_f32_16x16x32_bf16(af[m], bf[n], acc[m][n], 0, 0, 0);
        __builtin_amdgcn_s_setprio(0);
        __builtin_amdgcn_s_barrier();

        c += 1; if (c >= NBUF) c -= NBUF;
    }

    // epilogue: C/D layout col = lane&15, row = (lane>>4)*4 + reg
    #pragma unroll
    for (int m = 0; m < 4; ++m) {
        #pragma unroll
        for (int n = 0; n < 4; ++n) {
            int col  = col0 + wc * 64 + n * 16 + lr;
            int rowb = row0 + wr * 64 + m * 16 + lq * 4;
            #pragma unroll
            for (int j = 0; j < 4; ++j)
                C[(size_t)(rowb + j) * OUT_DIM + col] = acc[m][n][j] + 1e-5f;
        }
    }
}

extern "C" void kernel_launch(void* const* d_in, const int* in_sizes, int n_in,
                              void* d_out, int out_size, void* d_ws, size_t ws_size,
                              hipStream_t stream) {
    const float* x = (const float*)d_in[0];
    const float* W = (const float*)d_in[1];
    float* out = (float*)d_out;

    unsigned short* A  = (unsigned short*)d_ws;                              // 64 MB
    unsigned short* Bt = (unsigned short*)d_ws + (size_t)B_DIM * K_DIM;      // + 8 MB

    // allow 144 KiB dynamic LDS (no-op if already set / not required)
    (void)hipFuncSetAttribute((const void*)gemm_fused,
                              hipFuncAttributeMaxDynamicSharedMemorySize, LDS_BYTES);

    prep_x<<<4096, 256, 0, stream>>>(x, A);
    prep_w<<<dim3(OUT_DIM / 32, IN_DIM / 32), dim3(32, 8), 0, stream>>>(W, Bt);
    gemm_fused<<<(B_DIM / BM) * (OUT_DIM / BN), 512, LDS_BYTES, stream>>>(A, Bt, out);
}

// Round 3
// 93.136 us; speedup vs baseline: 1.3189x; 1.1500x over previous
//
#include <hip/hip_runtime.h>
#include <hip/hip_bf16.h>

typedef __attribute__((ext_vector_type(8))) short short8;
typedef __attribute__((ext_vector_type(4))) float f32x4;

#define B_DIM   8192
#define IN_DIM  2048
#define OUT_DIM 1024
#define K_DIM   (2 * IN_DIM)   // 4096: [masked x | -|x|] concat along K

#define BM 256
#define BN 128
#define BK 64
#define NT (K_DIM / BK)            // 64 K-tiles
#define A_TILE_E (BM * BK)         // 16384 bf16 = 32 KB
#define B_TILE_E (BN * BK)         // 8192  bf16 = 16 KB
#define NBUF 3
#define LDS_BYTES ((A_TILE_E + B_TILE_E) * NBUF * 2)   // 144 KiB

__device__ __forceinline__ unsigned short f2bf(float f) {
    union { float f; unsigned u; } v; v.f = f;
    unsigned u = v.u;
    unsigned r = (u + 0x7FFFu + ((u >> 16) & 1u)) >> 16;   // RNE
    return (unsigned short)r;
}

// A'[b][i] = x[b][i] if x >= -1 else 0 ; A'[b][IN+i] = -|x[b][i]|
__global__ void prep_x(const float* __restrict__ x, unsigned short* __restrict__ A) {
    const int n8 = B_DIM * IN_DIM / 8;
    for (int v = blockIdx.x * blockDim.x + threadIdx.x; v < n8;
         v += gridDim.x * blockDim.x) {
        const float4* xp = reinterpret_cast<const float4*>(x) + (size_t)v * 2;
        float4 lo = xp[0], hi = xp[1];
        float xs[8] = {lo.x, lo.y, lo.z, lo.w, hi.x, hi.y, hi.z, hi.w};
        short8 mv, av;
        #pragma unroll
        for (int j = 0; j < 8; ++j) {
            float xf = xs[j];
            mv[j] = (short)f2bf(xf >= -1.0f ? xf : 0.0f);
            av[j] = (short)f2bf(-fabsf(xf));
        }
        int b  = v >> 8;
        int i8 = v & 255;
        *reinterpret_cast<short8*>(A + (size_t)b * K_DIM + i8 * 8)          = mv;
        *reinterpret_cast<short8*>(A + (size_t)b * K_DIM + IN_DIM + i8 * 8) = av;
    }
}

// Bt[o][i] = W[i][o] ; Bt[o][IN+i] = 0.1*|W[i][o]|
__global__ void prep_w(const float* __restrict__ W, unsigned short* __restrict__ Bt) {
    __shared__ float tile[32][33];
    int o0 = blockIdx.x * 32;
    int i0 = blockIdx.y * 32;
    int tx = threadIdx.x, ty = threadIdx.y;   // 32 x 8
    #pragma unroll
    for (int r = 0; r < 4; ++r) {
        int ii = ty + r * 8;
        tile[ii][tx] = W[(size_t)(i0 + ii) * OUT_DIM + o0 + tx];
    }
    __syncthreads();
    #pragma unroll
    for (int r = 0; r < 4; ++r) {
        int oo = ty + r * 8;
        float wv = tile[tx][oo];
        Bt[(size_t)(o0 + oo) * K_DIM + i0 + tx]          = f2bf(wv);
        Bt[(size_t)(o0 + oo) * K_DIM + IN_DIM + i0 + tx] = f2bf(0.1f * fabsf(wv));
    }
}

// staging: linear LDS dest, XOR-swizzled global SOURCE slot (rule 21);
// ds_read applies the same involution.
__device__ __forceinline__ void stage_round(const unsigned short* __restrict__ gsrc,
                                            unsigned short* lds_base,
                                            int row_base, int k0, int r, int tid) {
    int c    = r * 512 + tid;
    int row  = c >> 3;
    int slot = (c & 7) ^ (row & 7);
    __builtin_amdgcn_global_load_lds(
        (const __attribute__((address_space(1))) void*)(gsrc + (size_t)(row_base + row) * K_DIM + k0 + slot * 8),
        (__attribute__((address_space(3))) void*)(lds_base + (size_t)c * 8),
        16, 0, 0);
}

// out[b][o] = sum_k A'[b][k] * Bt[o][k] + 1e-5
__global__ __launch_bounds__(512) void gemm_fused(const unsigned short* __restrict__ A,
                                                  const unsigned short* __restrict__ Bt,
                                                  float* __restrict__ C) {
    extern __shared__ __align__(16) unsigned short smem[];
    unsigned short* sA = smem;                       // [3][16384]
    unsigned short* sB = smem + NBUF * A_TILE_E;     // [3][8192]

    // XCD colocation: round-robin dispatch puts bid&7 on XCD bid&7.
    // Give each XCD a contiguous by-range so all 8 bx-blocks of a given
    // A-panel share one L2 (A fetched once per panel).
    int bid = blockIdx.x;
    int xcd = bid & 7;
    int idx = bid >> 3;            // 0..31
    int by  = xcd * 4 + (idx >> 3);
    int bx  = idx & 7;
    int row0 = by * BM;
    int col0 = bx * BN;

    int tid  = threadIdx.x;
    int lane = tid & 63;
    int w    = tid >> 6;           // 0..7
    int wr   = w >> 1;             // 0..3
    int wc   = w & 1;              // 0..1
    int lr   = lane & 15;
    int lq   = lane >> 4;          // 0..3

    f32x4 acc[4][4];
    #pragma unroll
    for (int m = 0; m < 4; ++m)
        #pragma unroll
        for (int n = 0; n < 4; ++n)
            acc[m][n] = (f32x4){0.f, 0.f, 0.f, 0.f};

    // prologue: stage tiles 0 and 1
    #pragma unroll
    for (int r = 0; r < 4; ++r) stage_round(A,  sA,            row0, 0,  r, tid);
    #pragma unroll
    for (int r = 0; r < 2; ++r) stage_round(Bt, sB,            col0, 0,  r, tid);
    #pragma unroll
    for (int r = 0; r < 4; ++r) stage_round(A,  sA + A_TILE_E, row0, BK, r, tid);
    #pragma unroll
    for (int r = 0; r < 2; ++r) stage_round(Bt, sB + B_TILE_E, col0, BK, r, tid);
    asm volatile("s_waitcnt vmcnt(6)" ::: "memory");
    __builtin_amdgcn_s_barrier();

    int c = 0;
    for (int t = 0; t < NT; ++t) {
        unsigned short* bufA = sA + c * A_TILE_E;
        unsigned short* bufB = sB + c * B_TILE_E;
        int c2 = c + 2; if (c2 >= NBUF) c2 -= NBUF;
        int k2 = (t + 2) * BK;
        bool pf = (t + 2) < NT;

        // issue prefetch for tile t+2 (buffer last read at t-1, safe after
        // the barrier that ended iteration t-1)
        if (pf) {
            stage_round(A,  sA + c2 * A_TILE_E, row0, k2, 0, tid);
            stage_round(A,  sA + c2 * A_TILE_E, row0, k2, 1, tid);
            stage_round(A,  sA + c2 * A_TILE_E, row0, k2, 2, tid);
            stage_round(A,  sA + c2 * A_TILE_E, row0, k2, 3, tid);
            stage_round(Bt, sB + c2 * B_TILE_E, col0, k2, 0, tid);
            stage_round(Bt, sB + c2 * B_TILE_E, col0, k2, 1, tid);
        }

        // all 16 frag reads for this K-tile; compiler interleaves with MFMA
        // via its own counted lgkmcnt (single inter-barrier region -> waves
        // slip against each other, LDS pipe overlaps MFMA pipe)
        short8 af[2][4], bf[2][4];
        #pragma unroll
        for (int kk = 0; kk < 2; ++kk) {
            #pragma unroll
            for (int m = 0; m < 4; ++m) {
                int ra = wr * 64 + m * 16 + lr;
                int sl = (kk * 4 + lq) ^ (ra & 7);
                af[kk][m] = *reinterpret_cast<const short8*>(bufA + ra * BK + (sl << 3));
            }
            #pragma unroll
            for (int n = 0; n < 4; ++n) {
                int rb = wc * 64 + n * 16 + lr;
                int sl = (kk * 4 + lq) ^ (rb & 7);
                bf[kk][n] = *reinterpret_cast<const short8*>(bufB + rb * BK + (sl << 3));
            }
        }

        __builtin_amdgcn_s_setprio(1);
        #pragma unroll
        for (int kk = 0; kk < 2; ++kk)
            #pragma unroll
            for (int m = 0; m < 4; ++m)
                #pragma unroll
                for (int n = 0; n < 4; ++n)
                    acc[m][n] = __builtin_amdgcn_mfma_f32_16x16x32_bf16(
                        af[kk][m], bf[kk][n], acc[m][n], 0, 0, 0);
        __builtin_amdgcn_s_setprio(0);

        // tile t+1 must be fully resident before anyone enters iter t+1;
        // keep t+2's 6 loads in flight (never drain to 0 mid-loop)
        if (pf) asm volatile("s_waitcnt vmcnt(6)" ::: "memory");
        else    asm volatile("s_waitcnt vmcnt(0)" ::: "memory");
        __builtin_amdgcn_s_barrier();

        c += 1; if (c >= NBUF) c -= NBUF;
    }

    // epilogue: C/D layout col = lane&15, row = (lane>>4)*4 + reg
    #pragma unroll
    for (int m = 0; m < 4; ++m) {
        #pragma unroll
        for (int n = 0; n < 4; ++n) {
            int col  = col0 + wc * 64 + n * 16 + lr;
            int rowb = row0 + wr * 64 + m * 16 + lq * 4;
            #pragma unroll
            for (int j = 0; j < 4; ++j)
                C[(size_t)(rowb + j) * OUT_DIM + col] = acc[m][n][j] + 1e-5f;
        }
    }
}

extern "C" void kernel_launch(void* const* d_in, const int* in_sizes, int n_in,
                              void* d_out, int out_size, void* d_ws, size_t ws_size,
                              hipStream_t stream) {
    const float* x = (const float*)d_in[0];
    const float* W = (const float*)d_in[1];
    float* out = (float*)d_out;

    unsigned short* A  = (unsigned short*)d_ws;                              // 64 MB
    unsigned short* Bt = (unsigned short*)d_ws + (size_t)B_DIM * K_DIM;      // + 8 MB

    (void)hipFuncSetAttribute((const void*)gemm_fused,
                              hipFuncAttributeMaxDynamicSharedMemorySize, LDS_BYTES);

    prep_x<<<4096, 256, 0, stream>>>(x, A);
    prep_w<<<dim3(OUT_DIM / 32, IN_DIM / 32), dim3(32, 8), 0, stream>>>(W, Bt);
    gemm_fused<<<(B_DIM / BM) * (OUT_DIM / BN), 512, LDS_BYTES, stream>>>(A, Bt, out);
}